// Round 10
// baseline (1491.175 us; speedup 1.0000x reference)
//
#include <hip/hip_runtime.h>

typedef __bf16 bf16;
typedef __attribute__((ext_vector_type(4))) __bf16 bf16x4;
typedef __attribute__((ext_vector_type(8))) __bf16 bf16x8;
typedef __attribute__((ext_vector_type(4))) float f32x4;

__device__ __forceinline__ void stage16(const bf16* g, bf16* l) {
  __builtin_amdgcn_global_load_lds(
      (const __attribute__((address_space(1))) void*)g,
      (__attribute__((address_space(3))) void*)l, 16, 0, 0);
}

// ============= convert+transpose (fp32 [R][C] -> bf16 [C][R]) =============
__global__ __launch_bounds__(256)
void transpose_f32_bf16(const float* __restrict__ src, bf16* __restrict__ dst, int R, int C)
{
  __shared__ bf16 tile[32][33];
  const int tx = threadIdx.x & 31, ty = threadIdx.x >> 5;
  const int c0 = blockIdx.x * 32, r0 = blockIdx.y * 32;
#pragma unroll
  for (int i = 0; i < 4; ++i)
    tile[ty + i * 8][tx] = (bf16)src[(size_t)(r0 + ty + i * 8) * C + c0 + tx];
  __syncthreads();
#pragma unroll
  for (int i = 0; i < 4; ++i)
    dst[(size_t)(c0 + ty + i * 8) * R + r0 + tx] = tile[tx][ty + i * 8];
}

// ============= layernorm: fp32 in -> bf16 out (one wave per 1024-col row) =============
__global__ __launch_bounds__(256)
void ln_f32_bf16(const float* __restrict__ x, const float* __restrict__ g,
                 const float* __restrict__ bta, bf16* __restrict__ out)
{
  const int row = blockIdx.x * 4 + (threadIdx.x >> 6);
  const int l = threadIdx.x & 63;
  const float* xr = x + (size_t)row * 1024 + l * 16;
  f32x4 a[4];
#pragma unroll
  for (int i = 0; i < 4; ++i) a[i] = ((const f32x4*)xr)[i];
  float s = 0.f, s2 = 0.f;
#pragma unroll
  for (int i = 0; i < 4; ++i)
#pragma unroll
    for (int jj = 0; jj < 4; ++jj) { float vv = a[i][jj]; s += vv; s2 += vv * vv; }
#pragma unroll
  for (int m = 1; m < 64; m <<= 1) { s += __shfl_xor(s, m); s2 += __shfl_xor(s2, m); }
  const float mu = s * (1.0f / 1024.0f);
  const float var = s2 * (1.0f / 1024.0f) - mu * mu;
  const float rs = rsqrtf(var + 1e-5f);
  f32x4 gv[4], bv[4];
#pragma unroll
  for (int i = 0; i < 4; ++i) {
    gv[i] = ((const f32x4*)(g + l * 16))[i];
    bv[i] = ((const f32x4*)(bta + l * 16))[i];
  }
  bf16x8 o0, o1;
#pragma unroll
  for (int i = 0; i < 8; ++i) {
    float v0 = a[i >> 2][i & 3];
    float v1 = a[2 + (i >> 2)][i & 3];
    o0[i] = (bf16)((v0 - mu) * rs * gv[i >> 2][i & 3] + bv[i >> 2][i & 3]);
    o1[i] = (bf16)((v1 - mu) * rs * gv[2 + (i >> 2)][i & 3] + bv[2 + (i >> 2)][i & 3]);
  }
  bf16* orow = out + (size_t)row * 1024 + l * 16;
  ((bf16x8*)orow)[0] = o0;
  ((bf16x8*)orow)[1] = o1;
}

// ======== GEMM 256x256, BK=32, 8 waves — r8 sync structure, scaled geometry ========
// Per K-step: 32 MFMA / 12 ds_read / 2 barriers (vs 16/8/2 at 128^2).
// LDS 64 KB total -> 2 blocks/CU. Same staging contract + zero-conflict swizzle as r8.
// EPI: 0 = fused QKV (seg0 q*0.125 [B,H,T,hd]; seg1 k; seg2 v [B,H,hd,T]);
//      4 = bf16 out = gelu(acc + bias) [tanh form].
template <int EPI>
__global__ __launch_bounds__(512, 4)
void gemm256b(const bf16* __restrict__ A, const bf16* __restrict__ Bt,
              const float* __restrict__ bias, const float* __restrict__ biasK,
              const float* __restrict__ biasV,
              void* __restrict__ out, void* __restrict__ outK, void* __restrict__ outV,
              int M, int N, int K)
{
  __shared__ bf16 As[2][256 * 32];   // 32 KB
  __shared__ bf16 Bs[2][256 * 32];   // 32 KB
  const int tid = threadIdx.x;
  const int l = tid & 63;
  const int w = tid >> 6;        // 0..7
  const int wm = w >> 2;         // 0..1: C rows [wm*128, +128)
  const int wn = w & 3;          // 0..3: C cols [wn*64, +64)
  const int m0 = blockIdx.x * 256;
  const int n0 = blockIdx.y * 256;

  // staging: thread t -> LDS row t>>2 (0..127, +128 second pass), 16B slot t&3
  // (lane-linear in LDS: wave w writes [w*1024 + l*16) -- gload_lds contract)
  const int srow = tid >> 2;
  const int sG8 = ((tid & 3) ^ ((tid >> 3) & 3)) * 8;   // pre-swizzled global slot
  const bf16* gA = A + (size_t)(m0 + srow) * K + sG8;
  const bf16* gB = Bt + (size_t)(n0 + srow) * K + sG8;
  const int ldsOff = srow * 32 + (tid & 3) * 8;

  const int lrow = l & 15;
  const int rdsl = ((l >> 4) ^ ((lrow >> 1) & 3)) * 8;  // swizzled read slot (elems)

  f32x4 acc[8][4] = {};
  const int KT = K >> 5;

#define STAGE(buf, k0)                                                 \
  do {                                                                 \
    stage16(gA + (k0), &As[buf][ldsOff]);                              \
    stage16(gA + (size_t)128 * K + (k0), &As[buf][4096 + ldsOff]);     \
    stage16(gB + (k0), &Bs[buf][ldsOff]);                              \
    stage16(gB + (size_t)128 * K + (k0), &Bs[buf][4096 + ldsOff]);     \
  } while (0)

  STAGE(0, 0);

  for (int kt = 0; kt < KT; ++kt) {
    const int cur = kt & 1;
    __builtin_amdgcn_s_barrier();            // B1: all waves done reading buf cur^1
    if (kt + 1 < KT) {
      STAGE(cur ^ 1, (kt + 1) << 5);         // 4 loads in flight across this K-step
      asm volatile("s_waitcnt vmcnt(4)" ::: "memory");   // tile kt's loads complete
    } else {
      asm volatile("s_waitcnt vmcnt(0)" ::: "memory");
    }
    __builtin_amdgcn_sched_barrier(0);
    __builtin_amdgcn_s_barrier();            // B2: everyone's tile-kt loads landed

    bf16x8 a[8], b[4];
#pragma unroll
    for (int mi = 0; mi < 8; ++mi)
      a[mi] = *(const bf16x8*)&As[cur][(wm * 128 + mi * 16 + lrow) * 32 + rdsl];
#pragma unroll
    for (int ni = 0; ni < 4; ++ni)
      b[ni] = *(const bf16x8*)&Bs[cur][(wn * 64 + ni * 16 + lrow) * 32 + rdsl];
    __builtin_amdgcn_s_setprio(1);
#pragma unroll
    for (int mi = 0; mi < 8; ++mi)
#pragma unroll
      for (int ni = 0; ni < 4; ++ni)
        acc[mi][ni] = __builtin_amdgcn_mfma_f32_16x16x32_bf16(a[mi], b[ni], acc[mi][ni], 0, 0, 0);
    __builtin_amdgcn_s_setprio(0);
  }
#undef STAGE

  // epilogue: C/D layout col = lane&15, row = (lane>>4)*4 + j
  const int seg = n0 >> 10;   // block-uniform (EPI 0; 256-tile never crosses seg)
  const float* bp = (EPI == 0) ? (seg == 0 ? bias : (seg == 1 ? biasK : biasV)) : bias;
#pragma unroll
  for (int mi = 0; mi < 8; ++mi) {
#pragma unroll
    for (int ni = 0; ni < 4; ++ni) {
      const int colg = n0 + wn * 64 + ni * 16 + lrow;
      const int col = (EPI == 0) ? (colg & 1023) : colg;
      const float bv = bp[col];
#pragma unroll
      for (int j = 0; j < 4; ++j) {
        const int row = m0 + wm * 128 + mi * 16 + (l >> 4) * 4 + j;
        float val = acc[mi][ni][j] + bv;
        if constexpr (EPI == 0) {
          const int bb = row >> 11, t = row & 2047, hh = col >> 6, d = col & 63;
          if (seg == 0)
            ((bf16*)out)[(((size_t)(bb * 16 + hh) * 2048 + t) * 64) + d] = (bf16)(val * 0.125f);
          else if (seg == 1)
            ((bf16*)outK)[(((size_t)(bb * 16 + hh) * 2048 + t) * 64) + d] = (bf16)val;
          else
            ((bf16*)outV)[(((size_t)(bb * 16 + hh) * 64 + d) * 2048) + t] = (bf16)val;
        } else if constexpr (EPI == 4) {
          const float u = 0.7978845608f * (val + 0.044715f * val * val * val);
          const float e = __expf(2.0f * u);
          const float th = 1.0f - 2.0f / (e + 1.0f);
          ((bf16*)out)[(size_t)row * N + col] = (bf16)(0.5f * val * (1.0f + th));
        }
      }
    }
  }
}

// ======== GEMM 128x128 (r8 proven): gll 3-buf depth-2 + counted vmcnt ========
// EPI: 3 = fp32 out = acc + bias + fp32 residual (proj);
//      5 = fp32 out = acc + bias + fp32 residual (final, K=4096).
template <int EPI>
__global__ __launch_bounds__(256)
void gemm_bt(const bf16* __restrict__ A, const bf16* __restrict__ Bt,
             const float* __restrict__ bias, void* __restrict__ out,
             const float* __restrict__ res, int M, int N, int K)
{
  __shared__ bf16 As[3][128 * 32];
  __shared__ bf16 Bs[3][128 * 32];
  const int tid = threadIdx.x;
  const int l = tid & 63;
  const int w = tid >> 6;
  const int wm = w >> 1, wn = w & 1;
  const int m0 = blockIdx.x * 128;
  const int n0 = blockIdx.y * 128;

  const int srow = tid >> 2;
  const int sG8 = ((tid & 3) ^ ((tid >> 3) & 3)) * 8;
  const bf16* gA = A + (size_t)(m0 + srow) * K + sG8;
  const bf16* gB = Bt + (size_t)(n0 + srow) * K + sG8;
  const int ldsOff = srow * 32 + (tid & 3) * 8;

  const int lrow = l & 15;
  const int rdsl = ((l >> 4) ^ ((lrow >> 1) & 3)) * 8;

  f32x4 acc[4][4] = {};
  const int KT = K >> 5;

#define STAGE(buf, k0)                                            \
  do {                                                            \
    stage16(gA + (k0), &As[buf][ldsOff]);                         \
    stage16(gA + (size_t)64 * K + (k0), &As[buf][2048 + ldsOff]); \
    stage16(gB + (k0), &Bs[buf][ldsOff]);                         \
    stage16(gB + (size_t)64 * K + (k0), &Bs[buf][2048 + ldsOff]); \
  } while (0)

  STAGE(0, 0);
  if (KT > 1) STAGE(1, 32);

  int cur = 0;
  for (int kt = 0; kt < KT; ++kt) {
    const int stg = (cur == 0) ? 2 : cur - 1;
    __builtin_amdgcn_s_barrier();
    if (kt + 2 < KT) {
      STAGE(stg, (kt + 2) << 5);
      asm volatile("s_waitcnt vmcnt(8)" ::: "memory");
    } else if (kt + 1 < KT) {
      asm volatile("s_waitcnt vmcnt(4)" ::: "memory");
    } else {
      asm volatile("s_waitcnt vmcnt(0)" ::: "memory");
    }
    __builtin_amdgcn_sched_barrier(0);
    __builtin_amdgcn_s_barrier();

    bf16x8 af[4], bfv[4];
#pragma unroll
    for (int i = 0; i < 4; ++i)
      af[i] = *(const bf16x8*)&As[cur][(wm * 64 + i * 16 + lrow) * 32 + rdsl];
#pragma unroll
    for (int i = 0; i < 4; ++i)
      bfv[i] = *(const bf16x8*)&Bs[cur][(wn * 64 + i * 16 + lrow) * 32 + rdsl];
#pragma unroll
    for (int mi = 0; mi < 4; ++mi)
#pragma unroll
      for (int ni = 0; ni < 4; ++ni)
        acc[mi][ni] = __builtin_amdgcn_mfma_f32_16x16x32_bf16(af[mi], bfv[ni], acc[mi][ni], 0, 0, 0);
    cur = (cur == 2) ? 0 : cur + 1;
  }
#undef STAGE

#pragma unroll
  for (int mi = 0; mi < 4; ++mi) {
#pragma unroll
    for (int ni = 0; ni < 4; ++ni) {
      const int col = n0 + wn * 64 + ni * 16 + lrow;
      const float bv = bias[col];
#pragma unroll
      for (int j = 0; j < 4; ++j) {
        const int row = m0 + wm * 64 + mi * 16 + (l >> 4) * 4 + j;
        float val = acc[mi][ni][j] + bv;
        if constexpr (EPI == 3 || EPI == 5) {
          ((float*)out)[(size_t)row * 1024 + col] = val + res[(size_t)row * 1024 + col];
        }
      }
    }
  }
}

// ======================= flash attention, swapped-QK^T + defer-max =======================
__global__ __launch_bounds__(512)
void attn_kernel(const bf16* __restrict__ q, const bf16* __restrict__ k,
                 const bf16* __restrict__ v, bf16* __restrict__ y,
                 const int* __restrict__ condp)
{
  __shared__ bf16 Ks[2][64 * 72];
  __shared__ bf16 Vs[2][64 * 72];
  __shared__ char PsB[8][2048];
  const int tid = threadIdx.x, l = tid & 63, w = tid >> 6;
  const int bx = blockIdx.x;
  const int qt = 15 - (bx >> 6);
  const int bh = bx & 63;
  const int bb = bh >> 4, hh = bh & 15;
  const int cond = condp[0];
  const int iLo = qt * 128;
  const size_t base = (size_t)bh * 2048 * 64;

  const int lrow = l & 15;
  const int g = l >> 4;
  const int lslot = g * 8;

  const int qrow = iLo + w * 16 + lrow;
  const bf16x8 bq0 = *(const bf16x8*)(q + base + (size_t)qrow * 64 + lslot);
  const bf16x8 bq1 = *(const bf16x8*)(q + base + (size_t)qrow * 64 + 32 + lslot);

  f32x4 o[4] = {};
  float m = -1e30f, lsum = 0.f;

  const int ckt = (cond + 63) >> 6;
  int nkt = ((iLo + 127) >> 6) + 1;
  if (nkt < ckt) nkt = ckt;
  const int wHi = iLo + w * 16 + 15;

  const int kr = tid >> 3;
  const int ks8 = (tid & 7) * 8;
  const bf16* kp = k + base + (size_t)kr * 64 + ks8;
  const bf16* vp = v + base + (size_t)kr * 2048 + ks8;

  bf16x8 rk = *(const bf16x8*)kp;
  bf16x8 rv = *(const bf16x8*)vp;
  *(bf16x8*)&Ks[0][kr * 72 + ks8] = rk;
  *(bf16x8*)&Vs[0][kr * 72 + ks8] = rv;
  __syncthreads();

  char* psw = PsB[w];

  for (int kt = 0; kt < nkt; ++kt) {
    const int cur = kt & 1;
    const int j0 = kt << 6;
    const bool pf = (kt + 1 < nkt);
    if (pf) {
      rk = *(const bf16x8*)(kp + (size_t)(j0 + 64) * 64);
      rv = *(const bf16x8*)(vp + j0 + 64);
    }

    const bool active = (j0 < cond) || (j0 <= wHi);
    if (active) {
      f32x4 sfr[4];
      __builtin_amdgcn_s_setprio(1);
#pragma unroll
      for (int nf = 0; nf < 4; ++nf) {
        f32x4 s = {};
        bf16x8 ka0 = *(const bf16x8*)&Ks[cur][(nf * 16 + lrow) * 72 + lslot];
        bf16x8 ka1 = *(const bf16x8*)&Ks[cur][(nf * 16 + lrow) * 72 + 32 + lslot];
        s = __builtin_amdgcn_mfma_f32_16x16x32_bf16(ka0, bq0, s, 0, 0, 0);
        s = __builtin_amdgcn_mfma_f32_16x16x32_bf16(ka1, bq1, s, 0, 0, 0);
        sfr[nf] = s;
      }
      __builtin_amdgcn_s_setprio(0);

      const bool safe = (j0 + 63 < cond) || (j0 + 63 <= iLo + w * 16);
      if (!safe) {
#pragma unroll
        for (int nf = 0; nf < 4; ++nf)
#pragma unroll
          for (int j = 0; j < 4; ++j) {
            const int kc = j0 + nf * 16 + g * 4 + j;
            const bool ok = (kc < cond) || (kc <= qrow);
            sfr[nf][j] = ok ? sfr[nf][j] : -1e30f;
          }
      }

      float pmax = sfr[0][0];
#pragma unroll
      for (int nf = 0; nf < 4; ++nf)
#pragma unroll
        for (int j = 0; j < 4; ++j) pmax = fmaxf(pmax, sfr[nf][j]);
      pmax = fmaxf(pmax, __shfl_xor(pmax, 16));
      pmax = fmaxf(pmax, __shfl_xor(pmax, 32));

      const bool resc = !__all(pmax - m <= 8.0f);
      if (resc) {
        const float mnew = fmaxf(m, pmax);
        const float alpha = __expf(m - mnew);
        m = mnew;
        lsum *= alpha;
        float ar[4];
#pragma unroll
        for (int j = 0; j < 4; ++j) ar[j] = __shfl(alpha, (l & 48) | (g * 4 + j));
#pragma unroll
        for (int df = 0; df < 4; ++df)
#pragma unroll
          for (int j = 0; j < 4; ++j) o[df][j] *= ar[j];
      }

      float rsum = 0.f;
#pragma unroll
      for (int nf = 0; nf < 4; ++nf) {
        bf16x4 pk;
#pragma unroll
        for (int j = 0; j < 4; ++j) {
          const float p = __expf(sfr[nf][j] - m);
          rsum += p;
          pk[j] = (bf16)p;
        }
        const int slot = 2 * nf + (g >> 1);
        const int boff = lrow * 128 + ((slot ^ (lrow & 7)) << 4) + (g & 1) * 8;
        *(bf16x4*)(psw + boff) = pk;
      }
      rsum += __shfl_xor(rsum, 16);
      rsum += __shfl_xor(rsum, 32);
      lsum += rsum;

      const int r0b = lrow * 128 + (((g) ^ (lrow & 7)) << 4);
      const int r1b = lrow * 128 + (((g + 4) ^ (lrow & 7)) << 4);
      const bf16x8 pa0 = *(const bf16x8*)(psw + r0b);
      const bf16x8 pa1 = *(const bf16x8*)(psw + r1b);
      __builtin_amdgcn_s_setprio(1);
#pragma unroll
      for (int df = 0; df < 4; ++df) {
        bf16x8 v0 = *(const bf16x8*)&Vs[cur][(df * 16 + lrow) * 72 + lslot];
        bf16x8 v1 = *(const bf16x8*)&Vs[cur][(df * 16 + lrow) * 72 + 32 + lslot];
        o[df] = __builtin_amdgcn_mfma_f32_16x16x32_bf16(pa0, v0, o[df], 0, 0, 0);
        o[df] = __builtin_amdgcn_mfma_f32_16x16x32_bf16(pa1, v1, o[df], 0, 0, 0);
      }
      __builtin_amdgcn_s_setprio(0);
    }

    if (pf) {
      *(bf16x8*)&Ks[cur ^ 1][kr * 72 + ks8] = rk;
      *(bf16x8*)&Vs[cur ^ 1][kr * 72 + ks8] = rv;
    }
    __syncthreads();
  }

  float lr[4];
#pragma unroll
  for (int j = 0; j < 4; ++j) lr[j] = 1.0f / __shfl(lsum, (l & 48) | (g * 4 + j));
#pragma unroll
  for (int df = 0; df < 4; ++df)
#pragma unroll
    for (int j = 0; j < 4; ++j) {
      const int irow = iLo + w * 16 + g * 4 + j;
      y[((size_t)bb * 2048 + irow) * 1024 + hh * 64 + df * 16 + lrow] = (bf16)(o[df][j] * lr[j]);
    }
}

// ======================= launcher =======================
extern "C" void kernel_launch(void* const* d_in, const int* in_sizes, int n_in,
                              void* d_out, int out_size, void* d_ws, size_t ws_size,
                              hipStream_t stream) {
  const float* x    = (const float*)d_in[0];
  const float* ln1g = (const float*)d_in[1];
  const float* ln1b = (const float*)d_in[2];
  const float* Wk   = (const float*)d_in[3];
  const float* bk   = (const float*)d_in[4];
  const float* Wq   = (const float*)d_in[5];
  const float* bq   = (const float*)d_in[6];
  const float* Wv   = (const float*)d_in[7];
  const float* bv   = (const float*)d_in[8];
  const float* Wp   = (const float*)d_in[9];
  const float* bpb  = (const float*)d_in[10];
  const float* ln2g = (const float*)d_in[11];
  const float* ln2b = (const float*)d_in[12];
  const float* W1   = (const float*)d_in[13];
  const float* b1   = (const float*)d_in[14];
  const float* W2   = (const float*)d_in[15];
  const float* b2   = (const float*)d_in[16];
  const int*  cond  = (const int*)d_in[17];
  float* out = (float*)d_out;

  char* ws = (char*)d_ws;
  const size_t MB = 1024ull * 1024ull;
  if (ws_size < 136 * MB) return;

  bf16*  WqkvT = (bf16*)(ws + 0 * MB);   // [3072][1024] bf16 = 6 MB
  bf16*  WpT   = (bf16*)(ws + 6 * MB);
  bf16*  W1T   = (bf16*)(ws + 8 * MB);
  bf16*  W2T   = (bf16*)(ws + 16 * MB);
  float* x2    = (float*)(ws + 24 * MB);
  bf16*  hbuf  = (bf16*)(ws + 56 * MB);
  bf16*  qb    = (bf16*)(ws + 72 * MB);
  bf16*  kb    = (bf16*)(ws + 88 * MB);
  bf16*  vb    = (bf16*)(ws + 104 * MB);
  bf16*  yb    = (bf16*)(ws + 120 * MB);
  bf16*  m1    = (bf16*)(ws + 72 * MB);  // reuses qb..yb (dead by FC1)

  dim3 blk(256);
  transpose_f32_bf16<<<dim3(32, 32), blk, 0, stream>>>(Wq, WqkvT,                1024, 1024);
  transpose_f32_bf16<<<dim3(32, 32), blk, 0, stream>>>(Wk, WqkvT + 1024 * 1024,  1024, 1024);
  transpose_f32_bf16<<<dim3(32, 32), blk, 0, stream>>>(Wv, WqkvT + 2048 * 1024,  1024, 1024);
  transpose_f32_bf16<<<dim3(32, 32), blk, 0, stream>>>(Wp, WpT, 1024, 1024);
  transpose_f32_bf16<<<dim3(128, 32), blk, 0, stream>>>(W1, W1T, 1024, 4096);
  transpose_f32_bf16<<<dim3(32, 128), blk, 0, stream>>>(W2, W2T, 4096, 1024);

  ln_f32_bf16<<<2048, blk, 0, stream>>>(x, ln1g, ln1b, hbuf);

  gemm256b<0><<<dim3(32, 12), dim3(512), 0, stream>>>(hbuf, WqkvT, bq, bk, bv,
                                                      qb, kb, vb, 8192, 3072, 1024);

  attn_kernel<<<dim3(1024), dim3(512), 0, stream>>>(qb, kb, vb, yb, cond);

  gemm_bt<3><<<dim3(64, 8), blk, 0, stream>>>(yb, WpT, bpb, x2, x, 8192, 1024, 1024);
  ln_f32_bf16<<<2048, blk, 0, stream>>>(x2, ln2g, ln2b, hbuf);
  gemm256b<4><<<dim3(32, 16), dim3(512), 0, stream>>>(hbuf, W1T, b1, nullptr, nullptr,
                                                      m1, nullptr, nullptr, 8192, 4096, 1024);
  gemm_bt<5><<<dim3(64, 8), blk, 0, stream>>>(m1, W2T, b2, out, x2, 8192, 1024, 4096);
}

// Round 11
// 440.431 us; speedup vs baseline: 3.3857x; 3.3857x over previous
//
#include <hip/hip_runtime.h>

typedef __bf16 bf16;
typedef __attribute__((ext_vector_type(4))) __bf16 bf16x4;
typedef __attribute__((ext_vector_type(8))) __bf16 bf16x8;
typedef __attribute__((ext_vector_type(4))) float f32x4;

__device__ __forceinline__ void stage16(const bf16* g, bf16* l) {
  __builtin_amdgcn_global_load_lds(
      (const __attribute__((address_space(1))) void*)g,
      (__attribute__((address_space(3))) void*)l, 16, 0, 0);
}

// ============= convert+transpose (fp32 [R][C] -> bf16 [C][R]) =============
__global__ __launch_bounds__(256)
void transpose_f32_bf16(const float* __restrict__ src, bf16* __restrict__ dst, int R, int C)
{
  __shared__ bf16 tile[32][33];
  const int tx = threadIdx.x & 31, ty = threadIdx.x >> 5;
  const int c0 = blockIdx.x * 32, r0 = blockIdx.y * 32;
#pragma unroll
  for (int i = 0; i < 4; ++i)
    tile[ty + i * 8][tx] = (bf16)src[(size_t)(r0 + ty + i * 8) * C + c0 + tx];
  __syncthreads();
#pragma unroll
  for (int i = 0; i < 4; ++i)
    dst[(size_t)(c0 + ty + i * 8) * R + r0 + tx] = tile[tx][ty + i * 8];
}

// ============= layernorm: fp32 in -> bf16 out (one wave per 1024-col row) =============
__global__ __launch_bounds__(256)
void ln_f32_bf16(const float* __restrict__ x, const float* __restrict__ g,
                 const float* __restrict__ bta, bf16* __restrict__ out)
{
  const int row = blockIdx.x * 4 + (threadIdx.x >> 6);
  const int l = threadIdx.x & 63;
  const float* xr = x + (size_t)row * 1024 + l * 16;
  f32x4 a[4];
#pragma unroll
  for (int i = 0; i < 4; ++i) a[i] = ((const f32x4*)xr)[i];
  float s = 0.f, s2 = 0.f;
#pragma unroll
  for (int i = 0; i < 4; ++i)
#pragma unroll
    for (int jj = 0; jj < 4; ++jj) { float vv = a[i][jj]; s += vv; s2 += vv * vv; }
#pragma unroll
  for (int m = 1; m < 64; m <<= 1) { s += __shfl_xor(s, m); s2 += __shfl_xor(s2, m); }
  const float mu = s * (1.0f / 1024.0f);
  const float var = s2 * (1.0f / 1024.0f) - mu * mu;
  const float rs = rsqrtf(var + 1e-5f);
  f32x4 gv[4], bv[4];
#pragma unroll
  for (int i = 0; i < 4; ++i) {
    gv[i] = ((const f32x4*)(g + l * 16))[i];
    bv[i] = ((const f32x4*)(bta + l * 16))[i];
  }
  bf16x8 o0, o1;
#pragma unroll
  for (int i = 0; i < 8; ++i) {
    float v0 = a[i >> 2][i & 3];
    float v1 = a[2 + (i >> 2)][i & 3];
    o0[i] = (bf16)((v0 - mu) * rs * gv[i >> 2][i & 3] + bv[i >> 2][i & 3]);
    o1[i] = (bf16)((v1 - mu) * rs * gv[2 + (i >> 2)][i & 3] + bv[2 + (i >> 2)][i & 3]);
  }
  bf16* orow = out + (size_t)row * 1024 + l * 16;
  ((bf16x8*)orow)[0] = o0;
  ((bf16x8*)orow)[1] = o1;
}

// ======== GEMM 256x256, BK=32, 8 waves — r8 sync structure, scaled geometry ========
// Per K-step: 32 MFMA / 12 ds_read / 2 barriers (vs 16/8/2 at 128^2).
// LDS 64 KB; VGPR free (no min-waves cap -> ~200-230, no spill), 1 block/CU.
// EPI: 0 = fused QKV (seg0 q*0.125 [B,H,T,hd]; seg1 k; seg2 v [B,H,hd,T]);
//      4 = bf16 out = gelu(acc + bias) [tanh form].
template <int EPI>
__global__ __launch_bounds__(512)
void gemm256b(const bf16* __restrict__ A, const bf16* __restrict__ Bt,
              const float* __restrict__ bias, const float* __restrict__ biasK,
              const float* __restrict__ biasV,
              void* __restrict__ out, void* __restrict__ outK, void* __restrict__ outV,
              int M, int N, int K)
{
  __shared__ bf16 As[2][256 * 32];   // 32 KB
  __shared__ bf16 Bs[2][256 * 32];   // 32 KB
  const int tid = threadIdx.x;
  const int l = tid & 63;
  const int w = tid >> 6;        // 0..7
  const int wm = w >> 2;         // 0..1: C rows [wm*128, +128)
  const int wn = w & 3;          // 0..3: C cols [wn*64, +64)
  const int m0 = blockIdx.x * 256;
  const int n0 = blockIdx.y * 256;

  // staging: thread t -> LDS row t>>2 (0..127, +128 second pass), 16B slot t&3
  // (lane-linear in LDS: wave w writes w*1024 + l*16 -- gload_lds contract)
  const int srow = tid >> 2;
  const int sG8 = ((tid & 3) ^ ((tid >> 3) & 3)) * 8;   // pre-swizzled global slot
  const bf16* gA = A + (size_t)(m0 + srow) * K + sG8;
  const bf16* gB = Bt + (size_t)(n0 + srow) * K + sG8;
  const int ldsOff = srow * 32 + (tid & 3) * 8;

  const int lrow = l & 15;
  const int rdsl = ((l >> 4) ^ ((lrow >> 1) & 3)) * 8;  // swizzled read slot (elems)

  f32x4 acc[8][4] = {};
  const int KT = K >> 5;

#define STAGE(buf, k0)                                                 \
  do {                                                                 \
    stage16(gA + (k0), &As[buf][ldsOff]);                              \
    stage16(gA + (size_t)128 * K + (k0), &As[buf][4096 + ldsOff]);     \
    stage16(gB + (k0), &Bs[buf][ldsOff]);                              \
    stage16(gB + (size_t)128 * K + (k0), &Bs[buf][4096 + ldsOff]);     \
  } while (0)

  STAGE(0, 0);

  for (int kt = 0; kt < KT; ++kt) {
    const int cur = kt & 1;
    __builtin_amdgcn_s_barrier();            // B1: all waves done reading buf cur^1
    if (kt + 1 < KT) {
      STAGE(cur ^ 1, (kt + 1) << 5);         // 4 loads in flight across this K-step
      asm volatile("s_waitcnt vmcnt(4)" ::: "memory");   // tile kt's loads complete
    } else {
      asm volatile("s_waitcnt vmcnt(0)" ::: "memory");
    }
    __builtin_amdgcn_sched_barrier(0);
    __builtin_amdgcn_s_barrier();            // B2: everyone's tile-kt loads landed

    bf16x8 a[8], b[4];
#pragma unroll
    for (int mi = 0; mi < 8; ++mi)
      a[mi] = *(const bf16x8*)&As[cur][(wm * 128 + mi * 16 + lrow) * 32 + rdsl];
#pragma unroll
    for (int ni = 0; ni < 4; ++ni)
      b[ni] = *(const bf16x8*)&Bs[cur][(wn * 64 + ni * 16 + lrow) * 32 + rdsl];
    __builtin_amdgcn_s_setprio(1);
#pragma unroll
    for (int mi = 0; mi < 8; ++mi)
#pragma unroll
      for (int ni = 0; ni < 4; ++ni)
        acc[mi][ni] = __builtin_amdgcn_mfma_f32_16x16x32_bf16(a[mi], b[ni], acc[mi][ni], 0, 0, 0);
    __builtin_amdgcn_s_setprio(0);
  }
#undef STAGE

  // epilogue: C/D layout col = lane&15, row = (lane>>4)*4 + j
  const int seg = n0 >> 10;   // block-uniform (EPI 0; 256-tile never crosses seg)
  const float* bp = (EPI == 0) ? (seg == 0 ? bias : (seg == 1 ? biasK : biasV)) : bias;
#pragma unroll
  for (int mi = 0; mi < 8; ++mi) {
#pragma unroll
    for (int ni = 0; ni < 4; ++ni) {
      const int colg = n0 + wn * 64 + ni * 16 + lrow;
      const int col = (EPI == 0) ? (colg & 1023) : colg;
      const float bv = bp[col];
#pragma unroll
      for (int j = 0; j < 4; ++j) {
        const int row = m0 + wm * 128 + mi * 16 + (l >> 4) * 4 + j;
        float val = acc[mi][ni][j] + bv;
        if constexpr (EPI == 0) {
          const int bb = row >> 11, t = row & 2047, hh = col >> 6, d = col & 63;
          if (seg == 0)
            ((bf16*)out)[(((size_t)(bb * 16 + hh) * 2048 + t) * 64) + d] = (bf16)(val * 0.125f);
          else if (seg == 1)
            ((bf16*)outK)[(((size_t)(bb * 16 + hh) * 2048 + t) * 64) + d] = (bf16)val;
          else
            ((bf16*)outV)[(((size_t)(bb * 16 + hh) * 64 + d) * 2048) + t] = (bf16)val;
        } else if constexpr (EPI == 4) {
          const float u = 0.7978845608f * (val + 0.044715f * val * val * val);
          const float e = __expf(2.0f * u);
          const float th = 1.0f - 2.0f / (e + 1.0f);
          ((bf16*)out)[(size_t)row * N + col] = (bf16)(0.5f * val * (1.0f + th));
        }
      }
    }
  }
}

// ======== GEMM 128x128 (r8 proven): gll 3-buf depth-2 + counted vmcnt ========
// EPI: 3 = fp32 out = acc + bias + fp32 residual (proj);
//      5 = fp32 out = acc + bias + fp32 residual (final, K=4096).
template <int EPI>
__global__ __launch_bounds__(256)
void gemm_bt(const bf16* __restrict__ A, const bf16* __restrict__ Bt,
             const float* __restrict__ bias, void* __restrict__ out,
             const float* __restrict__ res, int M, int N, int K)
{
  __shared__ bf16 As[3][128 * 32];
  __shared__ bf16 Bs[3][128 * 32];
  const int tid = threadIdx.x;
  const int l = tid & 63;
  const int w = tid >> 6;
  const int wm = w >> 1, wn = w & 1;
  const int m0 = blockIdx.x * 128;
  const int n0 = blockIdx.y * 128;

  const int srow = tid >> 2;
  const int sG8 = ((tid & 3) ^ ((tid >> 3) & 3)) * 8;
  const bf16* gA = A + (size_t)(m0 + srow) * K + sG8;
  const bf16* gB = Bt + (size_t)(n0 + srow) * K + sG8;
  const int ldsOff = srow * 32 + (tid & 3) * 8;

  const int lrow = l & 15;
  const int rdsl = ((l >> 4) ^ ((lrow >> 1) & 3)) * 8;

  f32x4 acc[4][4] = {};
  const int KT = K >> 5;

#define STAGE(buf, k0)                                            \
  do {                                                            \
    stage16(gA + (k0), &As[buf][ldsOff]);                         \
    stage16(gA + (size_t)64 * K + (k0), &As[buf][2048 + ldsOff]); \
    stage16(gB + (k0), &Bs[buf][ldsOff]);                         \
    stage16(gB + (size_t)64 * K + (k0), &Bs[buf][2048 + ldsOff]); \
  } while (0)

  STAGE(0, 0);
  if (KT > 1) STAGE(1, 32);

  int cur = 0;
  for (int kt = 0; kt < KT; ++kt) {
    const int stg = (cur == 0) ? 2 : cur - 1;
    __builtin_amdgcn_s_barrier();
    if (kt + 2 < KT) {
      STAGE(stg, (kt + 2) << 5);
      asm volatile("s_waitcnt vmcnt(8)" ::: "memory");
    } else if (kt + 1 < KT) {
      asm volatile("s_waitcnt vmcnt(4)" ::: "memory");
    } else {
      asm volatile("s_waitcnt vmcnt(0)" ::: "memory");
    }
    __builtin_amdgcn_sched_barrier(0);
    __builtin_amdgcn_s_barrier();

    bf16x8 af[4], bfv[4];
#pragma unroll
    for (int i = 0; i < 4; ++i)
      af[i] = *(const bf16x8*)&As[cur][(wm * 64 + i * 16 + lrow) * 32 + rdsl];
#pragma unroll
    for (int i = 0; i < 4; ++i)
      bfv[i] = *(const bf16x8*)&Bs[cur][(wn * 64 + i * 16 + lrow) * 32 + rdsl];
#pragma unroll
    for (int mi = 0; mi < 4; ++mi)
#pragma unroll
      for (int ni = 0; ni < 4; ++ni)
        acc[mi][ni] = __builtin_amdgcn_mfma_f32_16x16x32_bf16(af[mi], bfv[ni], acc[mi][ni], 0, 0, 0);
    cur = (cur == 2) ? 0 : cur + 1;
  }
#undef STAGE

#pragma unroll
  for (int mi = 0; mi < 4; ++mi) {
#pragma unroll
    for (int ni = 0; ni < 4; ++ni) {
      const int col = n0 + wn * 64 + ni * 16 + lrow;
      const float bv = bias[col];
#pragma unroll
      for (int j = 0; j < 4; ++j) {
        const int row = m0 + wm * 64 + mi * 16 + (l >> 4) * 4 + j;
        float val = acc[mi][ni][j] + bv;
        if constexpr (EPI == 3 || EPI == 5) {
          ((float*)out)[(size_t)row * 1024 + col] = val + res[(size_t)row * 1024 + col];
        }
      }
    }
  }
}

// ======================= flash attention, swapped-QK^T + defer-max =======================
__global__ __launch_bounds__(512)
void attn_kernel(const bf16* __restrict__ q, const bf16* __restrict__ k,
                 const bf16* __restrict__ v, bf16* __restrict__ y,
                 const int* __restrict__ condp)
{
  __shared__ bf16 Ks[2][64 * 72];
  __shared__ bf16 Vs[2][64 * 72];
  __shared__ char PsB[8][2048];
  const int tid = threadIdx.x, l = tid & 63, w = tid >> 6;
  const int bx = blockIdx.x;
  const int qt = 15 - (bx >> 6);
  const int bh = bx & 63;
  const int bb = bh >> 4, hh = bh & 15;
  const int cond = condp[0];
  const int iLo = qt * 128;
  const size_t base = (size_t)bh * 2048 * 64;

  const int lrow = l & 15;
  const int g = l >> 4;
  const int lslot = g * 8;

  const int qrow = iLo + w * 16 + lrow;
  const bf16x8 bq0 = *(const bf16x8*)(q + base + (size_t)qrow * 64 + lslot);
  const bf16x8 bq1 = *(const bf16x8*)(q + base + (size_t)qrow * 64 + 32 + lslot);

  f32x4 o[4] = {};
  float m = -1e30f, lsum = 0.f;

  const int ckt = (cond + 63) >> 6;
  int nkt = ((iLo + 127) >> 6) + 1;
  if (nkt < ckt) nkt = ckt;
  const int wHi = iLo + w * 16 + 15;

  const int kr = tid >> 3;
  const int ks8 = (tid & 7) * 8;
  const bf16* kp = k + base + (size_t)kr * 64 + ks8;
  const bf16* vp = v + base + (size_t)kr * 2048 + ks8;

  bf16x8 rk = *(const bf16x8*)kp;
  bf16x8 rv = *(const bf16x8*)vp;
  *(bf16x8*)&Ks[0][kr * 72 + ks8] = rk;
  *(bf16x8*)&Vs[0][kr * 72 + ks8] = rv;
  __syncthreads();

  char* psw = PsB[w];

  for (int kt = 0; kt < nkt; ++kt) {
    const int cur = kt & 1;
    const int j0 = kt << 6;
    const bool pf = (kt + 1 < nkt);
    if (pf) {
      rk = *(const bf16x8*)(kp + (size_t)(j0 + 64) * 64);
      rv = *(const bf16x8*)(vp + j0 + 64);
    }

    const bool active = (j0 < cond) || (j0 <= wHi);
    if (active) {
      f32x4 sfr[4];
      __builtin_amdgcn_s_setprio(1);
#pragma unroll
      for (int nf = 0; nf < 4; ++nf) {
        f32x4 s = {};
        bf16x8 ka0 = *(const bf16x8*)&Ks[cur][(nf * 16 + lrow) * 72 + lslot];
        bf16x8 ka1 = *(const bf16x8*)&Ks[cur][(nf * 16 + lrow) * 72 + 32 + lslot];
        s = __builtin_amdgcn_mfma_f32_16x16x32_bf16(ka0, bq0, s, 0, 0, 0);
        s = __builtin_amdgcn_mfma_f32_16x16x32_bf16(ka1, bq1, s, 0, 0, 0);
        sfr[nf] = s;
      }
      __builtin_amdgcn_s_setprio(0);

      const bool safe = (j0 + 63 < cond) || (j0 + 63 <= iLo + w * 16);
      if (!safe) {
#pragma unroll
        for (int nf = 0; nf < 4; ++nf)
#pragma unroll
          for (int j = 0; j < 4; ++j) {
            const int kc = j0 + nf * 16 + g * 4 + j;
            const bool ok = (kc < cond) || (kc <= qrow);
            sfr[nf][j] = ok ? sfr[nf][j] : -1e30f;
          }
      }

      float pmax = sfr[0][0];
#pragma unroll
      for (int nf = 0; nf < 4; ++nf)
#pragma unroll
        for (int j = 0; j < 4; ++j) pmax = fmaxf(pmax, sfr[nf][j]);
      pmax = fmaxf(pmax, __shfl_xor(pmax, 16));
      pmax = fmaxf(pmax, __shfl_xor(pmax, 32));

      const bool resc = !__all(pmax - m <= 8.0f);
      if (resc) {
        const float mnew = fmaxf(m, pmax);
        const float alpha = __expf(m - mnew);
        m = mnew;
        lsum *= alpha;
        float ar[4];
#pragma unroll
        for (int j = 0; j < 4; ++j) ar[j] = __shfl(alpha, (l & 48) | (g * 4 + j));
#pragma unroll
        for (int df = 0; df < 4; ++df)
#pragma unroll
          for (int j = 0; j < 4; ++j) o[df][j] *= ar[j];
      }

      float rsum = 0.f;
#pragma unroll
      for (int nf = 0; nf < 4; ++nf) {
        bf16x4 pk;
#pragma unroll
        for (int j = 0; j < 4; ++j) {
          const float p = __expf(sfr[nf][j] - m);
          rsum += p;
          pk[j] = (bf16)p;
        }
        const int slot = 2 * nf + (g >> 1);
        const int boff = lrow * 128 + ((slot ^ (lrow & 7)) << 4) + (g & 1) * 8;
        *(bf16x4*)(psw + boff) = pk;
      }
      rsum += __shfl_xor(rsum, 16);
      rsum += __shfl_xor(rsum, 32);
      lsum += rsum;

      const int r0b = lrow * 128 + (((g) ^ (lrow & 7)) << 4);
      const int r1b = lrow * 128 + (((g + 4) ^ (lrow & 7)) << 4);
      const bf16x8 pa0 = *(const bf16x8*)(psw + r0b);
      const bf16x8 pa1 = *(const bf16x8*)(psw + r1b);
      __builtin_amdgcn_s_setprio(1);
#pragma unroll
      for (int df = 0; df < 4; ++df) {
        bf16x8 v0 = *(const bf16x8*)&Vs[cur][(df * 16 + lrow) * 72 + lslot];
        bf16x8 v1 = *(const bf16x8*)&Vs[cur][(df * 16 + lrow) * 72 + 32 + lslot];
        o[df] = __builtin_amdgcn_mfma_f32_16x16x32_bf16(pa0, v0, o[df], 0, 0, 0);
        o[df] = __builtin_amdgcn_mfma_f32_16x16x32_bf16(pa1, v1, o[df], 0, 0, 0);
      }
      __builtin_amdgcn_s_setprio(0);
    }

    if (pf) {
      *(bf16x8*)&Ks[cur ^ 1][kr * 72 + ks8] = rk;
      *(bf16x8*)&Vs[cur ^ 1][kr * 72 + ks8] = rv;
    }
    __syncthreads();
  }

  float lr[4];
#pragma unroll
  for (int j = 0; j < 4; ++j) lr[j] = 1.0f / __shfl(lsum, (l & 48) | (g * 4 + j));
#pragma unroll
  for (int df = 0; df < 4; ++df)
#pragma unroll
    for (int j = 0; j < 4; ++j) {
      const int irow = iLo + w * 16 + g * 4 + j;
      y[((size_t)bb * 2048 + irow) * 1024 + hh * 64 + df * 16 + lrow] = (bf16)(o[df][j] * lr[j]);
    }
}

// ======================= launcher =======================
extern "C" void kernel_launch(void* const* d_in, const int* in_sizes, int n_in,
                              void* d_out, int out_size, void* d_ws, size_t ws_size,
                              hipStream_t stream) {
  const float* x    = (const float*)d_in[0];
  const float* ln1g = (const float*)d_in[1];
  const float* ln1b = (const float*)d_in[2];
  const float* Wk   = (const float*)d_in[3];
  const float* bk   = (const float*)d_in[4];
  const float* Wq   = (const float*)d_in[5];
  const float* bq   = (const float*)d_in[6];
  const float* Wv   = (const float*)d_in[7];
  const float* bv   = (const float*)d_in[8];
  const float* Wp   = (const float*)d_in[9];
  const float* bpb  = (const float*)d_in[10];
  const float* ln2g = (const float*)d_in[11];
  const float* ln2b = (const float*)d_in[12];
  const float* W1   = (const float*)d_in[13];
  const float* b1   = (const float*)d_in[14];
  const float* W2   = (const float*)d_in[15];
  const float* b2   = (const float*)d_in[16];
  const int*  cond  = (const int*)d_in[17];
  float* out = (float*)d_out;

  char* ws = (char*)d_ws;
  const size_t MB = 1024ull * 1024ull;
  if (ws_size < 136 * MB) return;

  bf16*  WqkvT = (bf16*)(ws + 0 * MB);   // [3072][1024] bf16 = 6 MB
  bf16*  WpT   = (bf16*)(ws + 6 * MB);
  bf16*  W1T   = (bf16*)(ws + 8 * MB);
  bf16*  W2T   = (bf16*)(ws + 16 * MB);
  float* x2    = (float*)(ws + 24 * MB);
  bf16*  hbuf  = (bf16*)(ws + 56 * MB);
  bf16*  qb    = (bf16*)(ws + 72 * MB);
  bf16*  kb    = (bf16*)(ws + 88 * MB);
  bf16*  vb    = (bf16*)(ws + 104 * MB);
  bf16*  yb    = (bf16*)(ws + 120 * MB);
  bf16*  m1    = (bf16*)(ws + 72 * MB);  // reuses qb..yb (dead by FC1)

  dim3 blk(256);
  transpose_f32_bf16<<<dim3(32, 32), blk, 0, stream>>>(Wq, WqkvT,                1024, 1024);
  transpose_f32_bf16<<<dim3(32, 32), blk, 0, stream>>>(Wk, WqkvT + 1024 * 1024,  1024, 1024);
  transpose_f32_bf16<<<dim3(32, 32), blk, 0, stream>>>(Wv, WqkvT + 2048 * 1024,  1024, 1024);
  transpose_f32_bf16<<<dim3(32, 32), blk, 0, stream>>>(Wp, WpT, 1024, 1024);
  transpose_f32_bf16<<<dim3(128, 32), blk, 0, stream>>>(W1, W1T, 1024, 4096);
  transpose_f32_bf16<<<dim3(32, 128), blk, 0, stream>>>(W2, W2T, 4096, 1024);

  ln_f32_bf16<<<2048, blk, 0, stream>>>(x, ln1g, ln1b, hbuf);

  gemm256b<0><<<dim3(32, 12), dim3(512), 0, stream>>>(hbuf, WqkvT, bq, bk, bv,
                                                      qb, kb, vb, 8192, 3072, 1024);

  attn_kernel<<<dim3(1024), dim3(512), 0, stream>>>(qb, kb, vb, yb, cond);

  gemm_bt<3><<<dim3(64, 8), blk, 0, stream>>>(yb, WpT, bpb, x2, x, 8192, 1024, 1024);
  ln_f32_bf16<<<2048, blk, 0, stream>>>(x2, ln2g, ln2b, hbuf);
  gemm256b<4><<<dim3(32, 16), dim3(512), 0, stream>>>(hbuf, W1T, b1, nullptr, nullptr,
                                                      m1, nullptr, nullptr, 8192, 4096, 1024);
  gemm_bt<5><<<dim3(64, 8), blk, 0, stream>>>(m1, W2T, b2, out, x2, 8192, 1024, 4096);
}

// Round 12
// 411.132 us; speedup vs baseline: 3.6270x; 1.0713x over previous
//
#include <hip/hip_runtime.h>

typedef __bf16 bf16;
typedef __attribute__((ext_vector_type(4))) __bf16 bf16x4;
typedef __attribute__((ext_vector_type(8))) __bf16 bf16x8;
typedef __attribute__((ext_vector_type(4))) float f32x4;

__device__ __forceinline__ void stage16(const bf16* g, bf16* l) {
  __builtin_amdgcn_global_load_lds(
      (const __attribute__((address_space(1))) void*)g,
      (__attribute__((address_space(3))) void*)l, 16, 0, 0);
}

// ============= convert+transpose (fp32 [R][C] -> bf16 [C][R]) =============
__global__ __launch_bounds__(256)
void transpose_f32_bf16(const float* __restrict__ src, bf16* __restrict__ dst, int R, int C)
{
  __shared__ bf16 tile[32][33];
  const int tx = threadIdx.x & 31, ty = threadIdx.x >> 5;
  const int c0 = blockIdx.x * 32, r0 = blockIdx.y * 32;
#pragma unroll
  for (int i = 0; i < 4; ++i)
    tile[ty + i * 8][tx] = (bf16)src[(size_t)(r0 + ty + i * 8) * C + c0 + tx];
  __syncthreads();
#pragma unroll
  for (int i = 0; i < 4; ++i)
    dst[(size_t)(c0 + ty + i * 8) * R + r0 + tx] = tile[tx][ty + i * 8];
}

// ============= layernorm: fp32 in -> bf16 out (one wave per 1024-col row) =============
__global__ __launch_bounds__(256)
void ln_f32_bf16(const float* __restrict__ x, const float* __restrict__ g,
                 const float* __restrict__ bta, bf16* __restrict__ out)
{
  const int row = blockIdx.x * 4 + (threadIdx.x >> 6);
  const int l = threadIdx.x & 63;
  const float* xr = x + (size_t)row * 1024 + l * 16;
  f32x4 a[4];
#pragma unroll
  for (int i = 0; i < 4; ++i) a[i] = ((const f32x4*)xr)[i];
  float s = 0.f, s2 = 0.f;
#pragma unroll
  for (int i = 0; i < 4; ++i)
#pragma unroll
    for (int jj = 0; jj < 4; ++jj) { float vv = a[i][jj]; s += vv; s2 += vv * vv; }
#pragma unroll
  for (int m = 1; m < 64; m <<= 1) { s += __shfl_xor(s, m); s2 += __shfl_xor(s2, m); }
  const float mu = s * (1.0f / 1024.0f);
  const float var = s2 * (1.0f / 1024.0f) - mu * mu;
  const float rs = rsqrtf(var + 1e-5f);
  f32x4 gv[4], bv[4];
#pragma unroll
  for (int i = 0; i < 4; ++i) {
    gv[i] = ((const f32x4*)(g + l * 16))[i];
    bv[i] = ((const f32x4*)(bta + l * 16))[i];
  }
  bf16x8 o0, o1;
#pragma unroll
  for (int i = 0; i < 8; ++i) {
    float v0 = a[i >> 2][i & 3];
    float v1 = a[2 + (i >> 2)][i & 3];
    o0[i] = (bf16)((v0 - mu) * rs * gv[i >> 2][i & 3] + bv[i >> 2][i & 3]);
    o1[i] = (bf16)((v1 - mu) * rs * gv[2 + (i >> 2)][i & 3] + bv[2 + (i >> 2)][i & 3]);
  }
  bf16* orow = out + (size_t)row * 1024 + l * 16;
  ((bf16x8*)orow)[0] = o0;
  ((bf16x8*)orow)[1] = o1;
}

// ======== GEMM 128x128, BK=32, 4 waves — exact T3 minimum 2-phase (m97 recipe) ========
// One __syncthreads per K-step; STAGE(next) issued BEFORE ds_read+MFMA of cur;
// barrier's implicit vmcnt(0)+lgkmcnt(0) drain completes next-tile loads and
// protects the buffer swap. No asm fences -> compiler pipelines ds_read<->MFMA.
// LDS 32 KB (2 buf) -> 3-4 blocks/CU (cross-block overlap hides the drain, m114).
// Zero-conflict swizzle pair (r6-verified): source pre-swizzle + swizzled read.
// EPI: 0 = fused QKV (seg0 q*0.125 [B,H,T,hd]; seg1 k; seg2 v [B,H,hd,T]);
//      3 = fp32 out = acc + bias + fp32 residual (proj);
//      4 = bf16 out = gelu(acc + bias) [tanh form];
//      5 = fp32 out = acc + bias + fp32 residual (final, K=4096).
template <int EPI>
__global__ __launch_bounds__(256)
void gemm_bt(const bf16* __restrict__ A, const bf16* __restrict__ Bt,
             const float* __restrict__ bias, const float* __restrict__ biasK,
             const float* __restrict__ biasV,
             void* __restrict__ out, void* __restrict__ outK, void* __restrict__ outV,
             const float* __restrict__ res, int M, int N, int K)
{
  __shared__ bf16 As[2][128 * 32];   // 16 KB
  __shared__ bf16 Bs[2][128 * 32];   // 16 KB
  const int tid = threadIdx.x;
  const int l = tid & 63;
  const int w = tid >> 6;
  const int wm = w >> 1, wn = w & 1;
  const int m0 = blockIdx.x * 128;
  const int n0 = blockIdx.y * 128;

  // staging: thread t -> LDS row t>>2, 16B slot t&3 (lane-linear, gll contract);
  // global col pre-swizzled so swizzled reads see the right data (rule #21)
  const int srow = tid >> 2;
  const int sG8 = ((tid & 3) ^ ((tid >> 3) & 3)) * 8;
  const bf16* gA = A + (size_t)(m0 + srow) * K + sG8;
  const bf16* gB = Bt + (size_t)(n0 + srow) * K + sG8;
  const int ldsOff = srow * 32 + (tid & 3) * 8;

  const int lrow = l & 15;
  const int rdsl = ((l >> 4) ^ ((lrow >> 1) & 3)) * 8;  // swizzled read slot (elems)

  f32x4 acc[4][4] = {};
  const int KT = K >> 5;

#define STAGE(buf, k0)                                            \
  do {                                                            \
    stage16(gA + (k0), &As[buf][ldsOff]);                         \
    stage16(gA + (size_t)64 * K + (k0), &As[buf][2048 + ldsOff]); \
    stage16(gB + (k0), &Bs[buf][ldsOff]);                         \
    stage16(gB + (size_t)64 * K + (k0), &Bs[buf][2048 + ldsOff]); \
  } while (0)

  STAGE(0, 0);

  for (int kt = 0; kt < KT; ++kt) {
    const int cur = kt & 1;
    __syncthreads();   // drains buf cur's stage (vmcnt0) + prev iter's reads
    if (kt + 1 < KT) STAGE(cur ^ 1, (kt + 1) << 5);   // fly across this compute

    bf16x8 af[4], bfv[4];
#pragma unroll
    for (int i = 0; i < 4; ++i)
      af[i] = *(const bf16x8*)&As[cur][(wm * 64 + i * 16 + lrow) * 32 + rdsl];
#pragma unroll
    for (int i = 0; i < 4; ++i)
      bfv[i] = *(const bf16x8*)&Bs[cur][(wn * 64 + i * 16 + lrow) * 32 + rdsl];
#pragma unroll
    for (int mi = 0; mi < 4; ++mi)
#pragma unroll
      for (int ni = 0; ni < 4; ++ni)
        acc[mi][ni] = __builtin_amdgcn_mfma_f32_16x16x32_bf16(af[mi], bfv[ni], acc[mi][ni], 0, 0, 0);
  }
#undef STAGE

  // epilogue: C/D layout col = lane&15, row = (lane>>4)*4 + j
  const int seg = n0 >> 10;   // block-uniform (EPI 0; 128-tile never crosses seg)
  const float* bp = (EPI == 0) ? (seg == 0 ? bias : (seg == 1 ? biasK : biasV)) : bias;
#pragma unroll
  for (int mi = 0; mi < 4; ++mi) {
#pragma unroll
    for (int ni = 0; ni < 4; ++ni) {
      const int colg = n0 + wn * 64 + ni * 16 + lrow;
      const int col = (EPI == 0) ? (colg & 1023) : colg;
      const float bv = bp[col];
#pragma unroll
      for (int j = 0; j < 4; ++j) {
        const int row = m0 + wm * 64 + mi * 16 + (l >> 4) * 4 + j;
        float val = acc[mi][ni][j] + bv;
        if constexpr (EPI == 0) {
          const int bb = row >> 11, t = row & 2047, hh = col >> 6, d = col & 63;
          if (seg == 0)
            ((bf16*)out)[(((size_t)(bb * 16 + hh) * 2048 + t) * 64) + d] = (bf16)(val * 0.125f);
          else if (seg == 1)
            ((bf16*)outK)[(((size_t)(bb * 16 + hh) * 2048 + t) * 64) + d] = (bf16)val;
          else
            ((bf16*)outV)[(((size_t)(bb * 16 + hh) * 64 + d) * 2048) + t] = (bf16)val;
        } else if constexpr (EPI == 3) {
          ((float*)out)[(size_t)row * 1024 + col] = val + res[(size_t)row * 1024 + col];
        } else if constexpr (EPI == 4) {
          const float u = 0.7978845608f * (val + 0.044715f * val * val * val);
          const float e = __expf(2.0f * u);
          const float th = 1.0f - 2.0f / (e + 1.0f);
          ((bf16*)out)[(size_t)row * N + col] = (bf16)(0.5f * val * (1.0f + th));
        } else if constexpr (EPI == 5) {
          ((float*)out)[(size_t)row * 1024 + col] = val + res[(size_t)row * 1024 + col];
        }
      }
    }
  }
}

// ======================= flash attention, swapped-QK^T + defer-max =======================
__global__ __launch_bounds__(512)
void attn_kernel(const bf16* __restrict__ q, const bf16* __restrict__ k,
                 const bf16* __restrict__ v, bf16* __restrict__ y,
                 const int* __restrict__ condp)
{
  __shared__ bf16 Ks[2][64 * 72];
  __shared__ bf16 Vs[2][64 * 72];
  __shared__ char PsB[8][2048];
  const int tid = threadIdx.x, l = tid & 63, w = tid >> 6;
  const int bx = blockIdx.x;
  const int qt = 15 - (bx >> 6);
  const int bh = bx & 63;
  const int bb = bh >> 4, hh = bh & 15;
  const int cond = condp[0];
  const int iLo = qt * 128;
  const size_t base = (size_t)bh * 2048 * 64;

  const int lrow = l & 15;
  const int g = l >> 4;
  const int lslot = g * 8;

  const int qrow = iLo + w * 16 + lrow;
  const bf16x8 bq0 = *(const bf16x8*)(q + base + (size_t)qrow * 64 + lslot);
  const bf16x8 bq1 = *(const bf16x8*)(q + base + (size_t)qrow * 64 + 32 + lslot);

  f32x4 o[4] = {};
  float m = -1e30f, lsum = 0.f;

  const int ckt = (cond + 63) >> 6;
  int nkt = ((iLo + 127) >> 6) + 1;
  if (nkt < ckt) nkt = ckt;
  const int wHi = iLo + w * 16 + 15;

  const int kr = tid >> 3;
  const int ks8 = (tid & 7) * 8;
  const bf16* kp = k + base + (size_t)kr * 64 + ks8;
  const bf16* vp = v + base + (size_t)kr * 2048 + ks8;

  bf16x8 rk = *(const bf16x8*)kp;
  bf16x8 rv = *(const bf16x8*)vp;
  *(bf16x8*)&Ks[0][kr * 72 + ks8] = rk;
  *(bf16x8*)&Vs[0][kr * 72 + ks8] = rv;
  __syncthreads();

  char* psw = PsB[w];

  for (int kt = 0; kt < nkt; ++kt) {
    const int cur = kt & 1;
    const int j0 = kt << 6;
    const bool pf = (kt + 1 < nkt);
    if (pf) {
      rk = *(const bf16x8*)(kp + (size_t)(j0 + 64) * 64);
      rv = *(const bf16x8*)(vp + j0 + 64);
    }

    const bool active = (j0 < cond) || (j0 <= wHi);
    if (active) {
      f32x4 sfr[4];
      __builtin_amdgcn_s_setprio(1);
#pragma unroll
      for (int nf = 0; nf < 4; ++nf) {
        f32x4 s = {};
        bf16x8 ka0 = *(const bf16x8*)&Ks[cur][(nf * 16 + lrow) * 72 + lslot];
        bf16x8 ka1 = *(const bf16x8*)&Ks[cur][(nf * 16 + lrow) * 72 + 32 + lslot];
        s = __builtin_amdgcn_mfma_f32_16x16x32_bf16(ka0, bq0, s, 0, 0, 0);
        s = __builtin_amdgcn_mfma_f32_16x16x32_bf16(ka1, bq1, s, 0, 0, 0);
        sfr[nf] = s;
      }
      __builtin_amdgcn_s_setprio(0);

      const bool safe = (j0 + 63 < cond) || (j0 + 63 <= iLo + w * 16);
      if (!safe) {
#pragma unroll
        for (int nf = 0; nf < 4; ++nf)
#pragma unroll
          for (int j = 0; j < 4; ++j) {
            const int kc = j0 + nf * 16 + g * 4 + j;
            const bool ok = (kc < cond) || (kc <= qrow);
            sfr[nf][j] = ok ? sfr[nf][j] : -1e30f;
          }
      }

      float pmax = sfr[0][0];
#pragma unroll
      for (int nf = 0; nf < 4; ++nf)
#pragma unroll
        for (int j = 0; j < 4; ++j) pmax = fmaxf(pmax, sfr[nf][j]);
      pmax = fmaxf(pmax, __shfl_xor(pmax, 16));
      pmax = fmaxf(pmax, __shfl_xor(pmax, 32));

      const bool resc = !__all(pmax - m <= 8.0f);
      if (resc) {
        const float mnew = fmaxf(m, pmax);
        const float alpha = __expf(m - mnew);
        m = mnew;
        lsum *= alpha;
        float ar[4];
#pragma unroll
        for (int j = 0; j < 4; ++j) ar[j] = __shfl(alpha, (l & 48) | (g * 4 + j));
#pragma unroll
        for (int df = 0; df < 4; ++df)
#pragma unroll
          for (int j = 0; j < 4; ++j) o[df][j] *= ar[j];
      }

      float rsum = 0.f;
#pragma unroll
      for (int nf = 0; nf < 4; ++nf) {
        bf16x4 pk;
#pragma unroll
        for (int j = 0; j < 4; ++j) {
          const float p = __expf(sfr[nf][j] - m);
          rsum += p;
          pk[j] = (bf16)p;
        }
        const int slot = 2 * nf + (g >> 1);
        const int boff = lrow * 128 + ((slot ^ (lrow & 7)) << 4) + (g & 1) * 8;
        *(bf16x4*)(psw + boff) = pk;
      }
      rsum += __shfl_xor(rsum, 16);
      rsum += __shfl_xor(rsum, 32);
      lsum += rsum;

      const int r0b = lrow * 128 + (((g) ^ (lrow & 7)) << 4);
      const int r1b = lrow * 128 + (((g + 4) ^ (lrow & 7)) << 4);
      const bf16x8 pa0 = *(const bf16x8*)(psw + r0b);
      const bf16x8 pa1 = *(const bf16x8*)(psw + r1b);
      __builtin_amdgcn_s_setprio(1);
#pragma unroll
      for (int df = 0; df < 4; ++df) {
        bf16x8 v0 = *(const bf16x8*)&Vs[cur][(df * 16 + lrow) * 72 + lslot];
        bf16x8 v1 = *(const bf16x8*)&Vs[cur][(df * 16 + lrow) * 72 + 32 + lslot];
        o[df] = __builtin_amdgcn_mfma_f32_16x16x32_bf16(pa0, v0, o[df], 0, 0, 0);
        o[df] = __builtin_amdgcn_mfma_f32_16x16x32_bf16(pa1, v1, o[df], 0, 0, 0);
      }
      __builtin_amdgcn_s_setprio(0);
    }

    if (pf) {
      *(bf16x8*)&Ks[cur ^ 1][kr * 72 + ks8] = rk;
      *(bf16x8*)&Vs[cur ^ 1][kr * 72 + ks8] = rv;
    }
    __syncthreads();
  }

  float lr[4];
#pragma unroll
  for (int j = 0; j < 4; ++j) lr[j] = 1.0f / __shfl(lsum, (l & 48) | (g * 4 + j));
#pragma unroll
  for (int df = 0; df < 4; ++df)
#pragma unroll
    for (int j = 0; j < 4; ++j) {
      const int irow = iLo + w * 16 + g * 4 + j;
      y[((size_t)bb * 2048 + irow) * 1024 + hh * 64 + df * 16 + lrow] = (bf16)(o[df][j] * lr[j]);
    }
}

// ======================= launcher =======================
extern "C" void kernel_launch(void* const* d_in, const int* in_sizes, int n_in,
                              void* d_out, int out_size, void* d_ws, size_t ws_size,
                              hipStream_t stream) {
  const float* x    = (const float*)d_in[0];
  const float* ln1g = (const float*)d_in[1];
  const float* ln1b = (const float*)d_in[2];
  const float* Wk   = (const float*)d_in[3];
  const float* bk   = (const float*)d_in[4];
  const float* Wq   = (const float*)d_in[5];
  const float* bq   = (const float*)d_in[6];
  const float* Wv   = (const float*)d_in[7];
  const float* bv   = (const float*)d_in[8];
  const float* Wp   = (const float*)d_in[9];
  const float* bpb  = (const float*)d_in[10];
  const float* ln2g = (const float*)d_in[11];
  const float* ln2b = (const float*)d_in[12];
  const float* W1   = (const float*)d_in[13];
  const float* b1   = (const float*)d_in[14];
  const float* W2   = (const float*)d_in[15];
  const float* b2   = (const float*)d_in[16];
  const int*  cond  = (const int*)d_in[17];
  float* out = (float*)d_out;

  char* ws = (char*)d_ws;
  const size_t MB = 1024ull * 1024ull;
  if (ws_size < 136 * MB) return;

  bf16*  WqkvT = (bf16*)(ws + 0 * MB);   // [3072][1024] bf16 = 6 MB
  bf16*  WpT   = (bf16*)(ws + 6 * MB);
  bf16*  W1T   = (bf16*)(ws + 8 * MB);
  bf16*  W2T   = (bf16*)(ws + 16 * MB);
  float* x2    = (float*)(ws + 24 * MB);
  bf16*  hbuf  = (bf16*)(ws + 56 * MB);
  bf16*  qb    = (bf16*)(ws + 72 * MB);
  bf16*  kb    = (bf16*)(ws + 88 * MB);
  bf16*  vb    = (bf16*)(ws + 104 * MB);
  bf16*  yb    = (bf16*)(ws + 120 * MB);
  bf16*  m1    = (bf16*)(ws + 72 * MB);  // reuses qb..yb (dead by FC1)

  dim3 blk(256);
  transpose_f32_bf16<<<dim3(32, 32), blk, 0, stream>>>(Wq, WqkvT,                1024, 1024);
  transpose_f32_bf16<<<dim3(32, 32), blk, 0, stream>>>(Wk, WqkvT + 1024 * 1024,  1024, 1024);
  transpose_f32_bf16<<<dim3(32, 32), blk, 0, stream>>>(Wv, WqkvT + 2048 * 1024,  1024, 1024);
  transpose_f32_bf16<<<dim3(32, 32), blk, 0, stream>>>(Wp, WpT, 1024, 1024);
  transpose_f32_bf16<<<dim3(128, 32), blk, 0, stream>>>(W1, W1T, 1024, 4096);
  transpose_f32_bf16<<<dim3(32, 128), blk, 0, stream>>>(W2, W2T, 4096, 1024);

  ln_f32_bf16<<<2048, blk, 0, stream>>>(x, ln1g, ln1b, hbuf);

  gemm_bt<0><<<dim3(64, 24), blk, 0, stream>>>(hbuf, WqkvT, bq, bk, bv,
                                               qb, kb, vb, nullptr, 8192, 3072, 1024);

  attn_kernel<<<dim3(1024), dim3(512), 0, stream>>>(qb, kb, vb, yb, cond);

  gemm_bt<3><<<dim3(64, 8), blk, 0, stream>>>(yb, WpT, bpb, nullptr, nullptr,
                                              x2, nullptr, nullptr, x, 8192, 1024, 1024);
  ln_f32_bf16<<<2048, blk, 0, stream>>>(x2, ln2g, ln2b, hbuf);
  gemm_bt<4><<<dim3(64, 32), blk, 0, stream>>>(hbuf, W1T, b1, nullptr, nullptr,
                                               m1, nullptr, nullptr, nullptr, 8192, 4096, 1024);
  gemm_bt<5><<<dim3(64, 8), blk, 0, stream>>>(m1, W2T, b2, nullptr, nullptr,
                                              out, nullptr, nullptr, x2, 8192, 1024, 4096);
}

// Round 13
// 388.758 us; speedup vs baseline: 3.8357x; 1.0576x over previous
//
#include <hip/hip_runtime.h>

typedef __bf16 bf16;
typedef __attribute__((ext_vector_type(4))) __bf16 bf16x4;
typedef __attribute__((ext_vector_type(8))) __bf16 bf16x8;
typedef __attribute__((ext_vector_type(4))) float f32x4;

__device__ __forceinline__ void stage16(const bf16* g, bf16* l) {
  __builtin_amdgcn_global_load_lds(
      (const __attribute__((address_space(1))) void*)g,
      (__attribute__((address_space(3))) void*)l, 16, 0, 0);
}

// ============= batched convert+transpose (fp32 [R][C] -> bf16 [C][R]) =============
__device__ __forceinline__ void tr_tile(const float* __restrict__ src, bf16* __restrict__ dst,
                                        int R, int C, int cx, int ry)
{
  __shared__ bf16 tile[32][33];
  const int tx = threadIdx.x & 31, ty = threadIdx.x >> 5;
  const int c0 = cx * 32, r0 = ry * 32;
#pragma unroll
  for (int i = 0; i < 4; ++i)
    tile[ty + i * 8][tx] = (bf16)src[(size_t)(r0 + ty + i * 8) * C + c0 + tx];
  __syncthreads();
#pragma unroll
  for (int i = 0; i < 4; ++i)
    dst[(size_t)(c0 + ty + i * 8) * R + r0 + tx] = tile[tx][ty + i * 8];
}

__global__ __launch_bounds__(256)
void transpose_all(const float* __restrict__ Wq, const float* __restrict__ Wk,
                   const float* __restrict__ Wv, const float* __restrict__ Wp,
                   const float* __restrict__ W1, const float* __restrict__ W2,
                   bf16* __restrict__ WqkvT, bf16* __restrict__ WpT,
                   bf16* __restrict__ W1T, bf16* __restrict__ W2T)
{
  const int id = blockIdx.x;
  if (id < 4096) {                       // four 1024x1024 mats, 1024 tiles each
    const int seg = id >> 10, t = id & 1023;
    const float* src = (seg == 0) ? Wq : (seg == 1) ? Wk : (seg == 2) ? Wv : Wp;
    bf16* dst = (seg == 3) ? WpT : (WqkvT + (size_t)seg * 1024 * 1024);
    tr_tile(src, dst, 1024, 1024, t & 31, t >> 5);
  } else if (id < 8192) {                // W1: R=1024, C=4096 -> grid 128 x 32
    const int t = id - 4096;
    tr_tile(W1, W1T, 1024, 4096, t & 127, t >> 7);
  } else {                               // W2: R=4096, C=1024 -> grid 32 x 128
    const int t = id - 8192;
    tr_tile(W2, W2T, 4096, 1024, t & 31, t >> 5);
  }
}

// ============= layernorm: fp32 in -> bf16 out (one wave per 1024-col row) =============
__global__ __launch_bounds__(256)
void ln_f32_bf16(const float* __restrict__ x, const float* __restrict__ g,
                 const float* __restrict__ bta, bf16* __restrict__ out)
{
  const int row = blockIdx.x * 4 + (threadIdx.x >> 6);
  const int l = threadIdx.x & 63;
  const float* xr = x + (size_t)row * 1024 + l * 16;
  f32x4 a[4];
#pragma unroll
  for (int i = 0; i < 4; ++i) a[i] = ((const f32x4*)xr)[i];
  float s = 0.f, s2 = 0.f;
#pragma unroll
  for (int i = 0; i < 4; ++i)
#pragma unroll
    for (int jj = 0; jj < 4; ++jj) { float vv = a[i][jj]; s += vv; s2 += vv * vv; }
#pragma unroll
  for (int m = 1; m < 64; m <<= 1) { s += __shfl_xor(s, m); s2 += __shfl_xor(s2, m); }
  const float mu = s * (1.0f / 1024.0f);
  const float var = s2 * (1.0f / 1024.0f) - mu * mu;
  const float rs = rsqrtf(var + 1e-5f);
  f32x4 gv[4], bv[4];
#pragma unroll
  for (int i = 0; i < 4; ++i) {
    gv[i] = ((const f32x4*)(g + l * 16))[i];
    bv[i] = ((const f32x4*)(bta + l * 16))[i];
  }
  bf16x8 o0, o1;
#pragma unroll
  for (int i = 0; i < 8; ++i) {
    float v0 = a[i >> 2][i & 3];
    float v1 = a[2 + (i >> 2)][i & 3];
    o0[i] = (bf16)((v0 - mu) * rs * gv[i >> 2][i & 3] + bv[i >> 2][i & 3]);
    o1[i] = (bf16)((v1 - mu) * rs * gv[2 + (i >> 2)][i & 3] + bv[2 + (i >> 2)][i & 3]);
  }
  bf16* orow = out + (size_t)row * 1024 + l * 16;
  ((bf16x8*)orow)[0] = o0;
  ((bf16x8*)orow)[1] = o1;
}

// ======== GEMM 256x128, BK=32, 8 waves — r12 schedule, higher intensity ========
// Same per-wave geometry (64x64 tile, 16 MFMA / 8 ds_read / K-step) and same
// single-__syncthreads schedule as the verified 128^2 kernel; block stages
// 24KB per K-step for 128 block-MFMA (5.3 MFMA/KB, +33% vs 128^2).
// LDS 48 KB -> 2-3 blocks/CU. Zero-conflict swizzle pair (r6-verified).
// EPI: 0 = fused QKV (seg0 q*0.125 [B,H,T,hd]; seg1 k; seg2 v [B,H,hd,T]);
//      4 = bf16 out = gelu(acc + bias) [tanh form].
template <int EPI>
__global__ __launch_bounds__(512)
void gemm_bt256(const bf16* __restrict__ A, const bf16* __restrict__ Bt,
                const float* __restrict__ bias, const float* __restrict__ biasK,
                const float* __restrict__ biasV,
                void* __restrict__ out, void* __restrict__ outK, void* __restrict__ outV,
                int M, int N, int K)
{
  __shared__ bf16 As[2][256 * 32];   // 32 KB
  __shared__ bf16 Bs[2][128 * 32];   // 16 KB
  const int tid = threadIdx.x;
  const int l = tid & 63;
  const int w = tid >> 6;        // 0..7
  const int wm = w >> 1;         // 0..3: C rows [wm*64, +64)
  const int wn = w & 1;          // 0..1: C cols [wn*64, +64)
  const int m0 = blockIdx.x * 256;
  const int n0 = blockIdx.y * 128;

  // staging: thread t -> LDS row t>>2 (0..127), 16B slot t&3 (lane-linear);
  // global col pre-swizzled to match the read swizzle (rule #21)
  const int srow = tid >> 2;
  const int sG8 = ((tid & 3) ^ ((tid >> 3) & 3)) * 8;
  const bf16* gA = A + (size_t)(m0 + srow) * K + sG8;
  const bf16* gB = Bt + (size_t)(n0 + srow) * K + sG8;
  const int ldsOff = srow * 32 + (tid & 3) * 8;

  const int lrow = l & 15;
  const int rdsl = ((l >> 4) ^ ((lrow >> 1) & 3)) * 8;  // swizzled read slot (elems)

  f32x4 acc[4][4] = {};
  const int KT = K >> 5;

#define STAGE(buf, k0)                                              \
  do {                                                              \
    stage16(gA + (k0), &As[buf][ldsOff]);                           \
    stage16(gA + (size_t)128 * K + (k0), &As[buf][4096 + ldsOff]);  \
    stage16(gB + (k0), &Bs[buf][ldsOff]);                           \
  } while (0)

  STAGE(0, 0);

  for (int kt = 0; kt < KT; ++kt) {
    const int cur = kt & 1;
    __syncthreads();   // drains buf cur's stage (vmcnt0) + prev iter's reads
    if (kt + 1 < KT) STAGE(cur ^ 1, (kt + 1) << 5);   // fly across this compute

    bf16x8 af[4], bfv[4];
#pragma unroll
    for (int i = 0; i < 4; ++i)
      af[i] = *(const bf16x8*)&As[cur][(wm * 64 + i * 16 + lrow) * 32 + rdsl];
#pragma unroll
    for (int i = 0; i < 4; ++i)
      bfv[i] = *(const bf16x8*)&Bs[cur][(wn * 64 + i * 16 + lrow) * 32 + rdsl];
#pragma unroll
    for (int mi = 0; mi < 4; ++mi)
#pragma unroll
      for (int ni = 0; ni < 4; ++ni)
        acc[mi][ni] = __builtin_amdgcn_mfma_f32_16x16x32_bf16(af[mi], bfv[ni], acc[mi][ni], 0, 0, 0);
  }
#undef STAGE

  // epilogue: C/D layout col = lane&15, row = (lane>>4)*4 + j
  const int seg = n0 >> 10;   // block-uniform (128-wide tile never crosses seg)
  const float* bp = (EPI == 0) ? (seg == 0 ? bias : (seg == 1 ? biasK : biasV)) : bias;
#pragma unroll
  for (int mi = 0; mi < 4; ++mi) {
#pragma unroll
    for (int ni = 0; ni < 4; ++ni) {
      const int colg = n0 + wn * 64 + ni * 16 + lrow;
      const int col = (EPI == 0) ? (colg & 1023) : colg;
      const float bv = bp[col];
#pragma unroll
      for (int j = 0; j < 4; ++j) {
        const int row = m0 + wm * 64 + mi * 16 + (l >> 4) * 4 + j;
        float val = acc[mi][ni][j] + bv;
        if constexpr (EPI == 0) {
          const int bb = row >> 11, t = row & 2047, hh = col >> 6, d = col & 63;
          if (seg == 0)
            ((bf16*)out)[(((size_t)(bb * 16 + hh) * 2048 + t) * 64) + d] = (bf16)(val * 0.125f);
          else if (seg == 1)
            ((bf16*)outK)[(((size_t)(bb * 16 + hh) * 2048 + t) * 64) + d] = (bf16)val;
          else
            ((bf16*)outV)[(((size_t)(bb * 16 + hh) * 64 + d) * 2048) + t] = (bf16)val;
        } else if constexpr (EPI == 4) {
          const float u = 0.7978845608f * (val + 0.044715f * val * val * val);
          const float e = __expf(2.0f * u);
          const float th = 1.0f - 2.0f / (e + 1.0f);
          ((bf16*)out)[(size_t)row * N + col] = (bf16)(0.5f * val * (1.0f + th));
        }
      }
    }
  }
}

// ======== GEMM 128x128, BK=32, 4 waves — r12 proven (proj / FC2) ========
// EPI: 3 = fp32 out = acc + bias + fp32 residual (proj);
//      5 = fp32 out = acc + bias + fp32 residual (final, K=4096).
template <int EPI>
__global__ __launch_bounds__(256)
void gemm_bt(const bf16* __restrict__ A, const bf16* __restrict__ Bt,
             const float* __restrict__ bias, void* __restrict__ out,
             const float* __restrict__ res, int M, int N, int K)
{
  __shared__ bf16 As[2][128 * 32];   // 16 KB
  __shared__ bf16 Bs[2][128 * 32];   // 16 KB
  const int tid = threadIdx.x;
  const int l = tid & 63;
  const int w = tid >> 6;
  const int wm = w >> 1, wn = w & 1;
  const int m0 = blockIdx.x * 128;
  const int n0 = blockIdx.y * 128;

  const int srow = tid >> 2;
  const int sG8 = ((tid & 3) ^ ((tid >> 3) & 3)) * 8;
  const bf16* gA = A + (size_t)(m0 + srow) * K + sG8;
  const bf16* gB = Bt + (size_t)(n0 + srow) * K + sG8;
  const int ldsOff = srow * 32 + (tid & 3) * 8;

  const int lrow = l & 15;
  const int rdsl = ((l >> 4) ^ ((lrow >> 1) & 3)) * 8;

  f32x4 acc[4][4] = {};
  const int KT = K >> 5;

#define STAGE(buf, k0)                                            \
  do {                                                            \
    stage16(gA + (k0), &As[buf][ldsOff]);                         \
    stage16(gA + (size_t)64 * K + (k0), &As[buf][2048 + ldsOff]); \
    stage16(gB + (k0), &Bs[buf][ldsOff]);                         \
    stage16(gB + (size_t)64 * K + (k0), &Bs[buf][2048 + ldsOff]); \
  } while (0)

  STAGE(0, 0);

  for (int kt = 0; kt < KT; ++kt) {
    const int cur = kt & 1;
    __syncthreads();
    if (kt + 1 < KT) STAGE(cur ^ 1, (kt + 1) << 5);

    bf16x8 af[4], bfv[4];
#pragma unroll
    for (int i = 0; i < 4; ++i)
      af[i] = *(const bf16x8*)&As[cur][(wm * 64 + i * 16 + lrow) * 32 + rdsl];
#pragma unroll
    for (int i = 0; i < 4; ++i)
      bfv[i] = *(const bf16x8*)&Bs[cur][(wn * 64 + i * 16 + lrow) * 32 + rdsl];
#pragma unroll
    for (int mi = 0; mi < 4; ++mi)
#pragma unroll
      for (int ni = 0; ni < 4; ++ni)
        acc[mi][ni] = __builtin_amdgcn_mfma_f32_16x16x32_bf16(af[mi], bfv[ni], acc[mi][ni], 0, 0, 0);
  }
#undef STAGE

#pragma unroll
  for (int mi = 0; mi < 4; ++mi) {
#pragma unroll
    for (int ni = 0; ni < 4; ++ni) {
      const int col = n0 + wn * 64 + ni * 16 + lrow;
      const float bv = bias[col];
#pragma unroll
      for (int j = 0; j < 4; ++j) {
        const int row = m0 + wm * 64 + mi * 16 + (l >> 4) * 4 + j;
        float val = acc[mi][ni][j] + bv;
        if constexpr (EPI == 3 || EPI == 5) {
          ((float*)out)[(size_t)row * 1024 + col] = val + res[(size_t)row * 1024 + col];
        }
      }
    }
  }
}

// ======================= flash attention, swapped-QK^T + defer-max =======================
__global__ __launch_bounds__(512)
void attn_kernel(const bf16* __restrict__ q, const bf16* __restrict__ k,
                 const bf16* __restrict__ v, bf16* __restrict__ y,
                 const int* __restrict__ condp)
{
  __shared__ bf16 Ks[2][64 * 72];
  __shared__ bf16 Vs[2][64 * 72];
  __shared__ char PsB[8][2048];
  const int tid = threadIdx.x, l = tid & 63, w = tid >> 6;
  const int bx = blockIdx.x;
  const int qt = 15 - (bx >> 6);
  const int bh = bx & 63;
  const int bb = bh >> 4, hh = bh & 15;
  const int cond = condp[0];
  const int iLo = qt * 128;
  const size_t base = (size_t)bh * 2048 * 64;

  const int lrow = l & 15;
  const int g = l >> 4;
  const int lslot = g * 8;

  const int qrow = iLo + w * 16 + lrow;
  const bf16x8 bq0 = *(const bf16x8*)(q + base + (size_t)qrow * 64 + lslot);
  const bf16x8 bq1 = *(const bf16x8*)(q + base + (size_t)qrow * 64 + 32 + lslot);

  f32x4 o[4] = {};
  float m = -1e30f, lsum = 0.f;

  const int ckt = (cond + 63) >> 6;
  int nkt = ((iLo + 127) >> 6) + 1;
  if (nkt < ckt) nkt = ckt;
  const int wHi = iLo + w * 16 + 15;

  const int kr = tid >> 3;
  const int ks8 = (tid & 7) * 8;
  const bf16* kp = k + base + (size_t)kr * 64 + ks8;
  const bf16* vp = v + base + (size_t)kr * 2048 + ks8;

  bf16x8 rk = *(const bf16x8*)kp;
  bf16x8 rv = *(const bf16x8*)vp;
  *(bf16x8*)&Ks[0][kr * 72 + ks8] = rk;
  *(bf16x8*)&Vs[0][kr * 72 + ks8] = rv;
  __syncthreads();

  char* psw = PsB[w];

  for (int kt = 0; kt < nkt; ++kt) {
    const int cur = kt & 1;
    const int j0 = kt << 6;
    const bool pf = (kt + 1 < nkt);
    if (pf) {
      rk = *(const bf16x8*)(kp + (size_t)(j0 + 64) * 64);
      rv = *(const bf16x8*)(vp + j0 + 64);
    }

    const bool active = (j0 < cond) || (j0 <= wHi);
    if (active) {
      f32x4 sfr[4];
      __builtin_amdgcn_s_setprio(1);
#pragma unroll
      for (int nf = 0; nf < 4; ++nf) {
        f32x4 s = {};
        bf16x8 ka0 = *(const bf16x8*)&Ks[cur][(nf * 16 + lrow) * 72 + lslot];
        bf16x8 ka1 = *(const bf16x8*)&Ks[cur][(nf * 16 + lrow) * 72 + 32 + lslot];
        s = __builtin_amdgcn_mfma_f32_16x16x32_bf16(ka0, bq0, s, 0, 0, 0);
        s = __builtin_amdgcn_mfma_f32_16x16x32_bf16(ka1, bq1, s, 0, 0, 0);
        sfr[nf] = s;
      }
      __builtin_amdgcn_s_setprio(0);

      const bool safe = (j0 + 63 < cond) || (j0 + 63 <= iLo + w * 16);
      if (!safe) {
#pragma unroll
        for (int nf = 0; nf < 4; ++nf)
#pragma unroll
          for (int j = 0; j < 4; ++j) {
            const int kc = j0 + nf * 16 + g * 4 + j;
            const bool ok = (kc < cond) || (kc <= qrow);
            sfr[nf][j] = ok ? sfr[nf][j] : -1e30f;
          }
      }

      float pmax = sfr[0][0];
#pragma unroll
      for (int nf = 0; nf < 4; ++nf)
#pragma unroll
        for (int j = 0; j < 4; ++j) pmax = fmaxf(pmax, sfr[nf][j]);
      pmax = fmaxf(pmax, __shfl_xor(pmax, 16));
      pmax = fmaxf(pmax, __shfl_xor(pmax, 32));

      const bool resc = !__all(pmax - m <= 8.0f);
      if (resc) {
        const float mnew = fmaxf(m, pmax);
        const float alpha = __expf(m - mnew);
        m = mnew;
        lsum *= alpha;
        float ar[4];
#pragma unroll
        for (int j = 0; j < 4; ++j) ar[j] = __shfl(alpha, (l & 48) | (g * 4 + j));
#pragma unroll
        for (int df = 0; df < 4; ++df)
#pragma unroll
          for (int j = 0; j < 4; ++j) o[df][j] *= ar[j];
      }

      float rsum = 0.f;
#pragma unroll
      for (int nf = 0; nf < 4; ++nf) {
        bf16x4 pk;
#pragma unroll
        for (int j = 0; j < 4; ++j) {
          const float p = __expf(sfr[nf][j] - m);
          rsum += p;
          pk[j] = (bf16)p;
        }
        const int slot = 2 * nf + (g >> 1);
        const int boff = lrow * 128 + ((slot ^ (lrow & 7)) << 4) + (g & 1) * 8;
        *(bf16x4*)(psw + boff) = pk;
      }
      rsum += __shfl_xor(rsum, 16);
      rsum += __shfl_xor(rsum, 32);
      lsum += rsum;

      const int r0b = lrow * 128 + (((g) ^ (lrow & 7)) << 4);
      const int r1b = lrow * 128 + (((g + 4) ^ (lrow & 7)) << 4);
      const bf16x8 pa0 = *(const bf16x8*)(psw + r0b);
      const bf16x8 pa1 = *(const bf16x8*)(psw + r1b);
      __builtin_amdgcn_s_setprio(1);
#pragma unroll
      for (int df = 0; df < 4; ++df) {
        bf16x8 v0 = *(const bf16x8*)&Vs[cur][(df * 16 + lrow) * 72 + lslot];
        bf16x8 v1 = *(const bf16x8*)&Vs[cur][(df * 16 + lrow) * 72 + 32 + lslot];
        o[df] = __builtin_amdgcn_mfma_f32_16x16x32_bf16(pa0, v0, o[df], 0, 0, 0);
        o[df] = __builtin_amdgcn_mfma_f32_16x16x32_bf16(pa1, v1, o[df], 0, 0, 0);
      }
      __builtin_amdgcn_s_setprio(0);
    }

    if (pf) {
      *(bf16x8*)&Ks[cur ^ 1][kr * 72 + ks8] = rk;
      *(bf16x8*)&Vs[cur ^ 1][kr * 72 + ks8] = rv;
    }
    __syncthreads();
  }

  float lr[4];
#pragma unroll
  for (int j = 0; j < 4; ++j) lr[j] = 1.0f / __shfl(lsum, (l & 48) | (g * 4 + j));
#pragma unroll
  for (int df = 0; df < 4; ++df)
#pragma unroll
    for (int j = 0; j < 4; ++j) {
      const int irow = iLo + w * 16 + g * 4 + j;
      y[((size_t)bb * 2048 + irow) * 1024 + hh * 64 + df * 16 + lrow] = (bf16)(o[df][j] * lr[j]);
    }
}

// ======================= launcher =======================
extern "C" void kernel_launch(void* const* d_in, const int* in_sizes, int n_in,
                              void* d_out, int out_size, void* d_ws, size_t ws_size,
                              hipStream_t stream) {
  const float* x    = (const float*)d_in[0];
  const float* ln1g = (const float*)d_in[1];
  const float* ln1b = (const float*)d_in[2];
  const float* Wk   = (const float*)d_in[3];
  const float* bk   = (const float*)d_in[4];
  const float* Wq   = (const float*)d_in[5];
  const float* bq   = (const float*)d_in[6];
  const float* Wv   = (const float*)d_in[7];
  const float* bv   = (const float*)d_in[8];
  const float* Wp   = (const float*)d_in[9];
  const float* bpb  = (const float*)d_in[10];
  const float* ln2g = (const float*)d_in[11];
  const float* ln2b = (const float*)d_in[12];
  const float* W1   = (const float*)d_in[13];
  const float* b1   = (const float*)d_in[14];
  const float* W2   = (const float*)d_in[15];
  const float* b2   = (const float*)d_in[16];
  const int*  cond  = (const int*)d_in[17];
  float* out = (float*)d_out;

  char* ws = (char*)d_ws;
  const size_t MB = 1024ull * 1024ull;
  if (ws_size < 136 * MB) return;

  bf16*  WqkvT = (bf16*)(ws + 0 * MB);   // [3072][1024] bf16 = 6 MB
  bf16*  WpT   = (bf16*)(ws + 6 * MB);
  bf16*  W1T   = (bf16*)(ws + 8 * MB);
  bf16*  W2T   = (bf16*)(ws + 16 * MB);
  float* x2    = (float*)(ws + 24 * MB);
  bf16*  hbuf  = (bf16*)(ws + 56 * MB);
  bf16*  qb    = (bf16*)(ws + 72 * MB);
  bf16*  kb    = (bf16*)(ws + 88 * MB);
  bf16*  vb    = (bf16*)(ws + 104 * MB);
  bf16*  yb    = (bf16*)(ws + 120 * MB);
  bf16*  m1    = (bf16*)(ws + 72 * MB);  // reuses qb..yb (dead by FC1)

  dim3 blk(256);
  transpose_all<<<dim3(12288), blk, 0, stream>>>(Wq, Wk, Wv, Wp, W1, W2,
                                                 WqkvT, WpT, W1T, W2T);

  ln_f32_bf16<<<2048, blk, 0, stream>>>(x, ln1g, ln1b, hbuf);

  gemm_bt256<0><<<dim3(32, 24), dim3(512), 0, stream>>>(hbuf, WqkvT, bq, bk, bv,
                                                        qb, kb, vb, 8192, 3072, 1024);

  attn_kernel<<<dim3(1024), dim3(512), 0, stream>>>(qb, kb, vb, yb, cond);

  gemm_bt<3><<<dim3(64, 8), blk, 0, stream>>>(yb, WpT, bpb, x2, x, 8192, 1024, 1024);
  ln_f32_bf16<<<2048, blk, 0, stream>>>(x2, ln2g, ln2b, hbuf);
  gemm_bt256<4><<<dim3(32, 32), dim3(512), 0, stream>>>(hbuf, W1T, b1, nullptr, nullptr,
                                                        m1, nullptr, nullptr, 8192, 4096, 1024);
  gemm_bt<5><<<dim3(64, 8), blk, 0, stream>>>(m1, W2T, b2, out, x2, 8192, 1024, 4096);
}